// Round 11
// baseline (181.828 us; speedup 1.0000x reference)
//
#include <hip/hip_runtime.h>
#include <math.h>

// BatchHardTripletMarginLoss on MI355X — round 11: stage-once 64x64 mine.
// Pipeline (all on `stream`, graph-capture safe):
//   prep    : [blocks 0..1023] E fp32->fp16 + sq
//             [blocks 1024..5119] per-block mask-format sniff + positives_mask
//             -> packed bitmask (16-B loads + shuffle-OR; neg = ~(pos|eye))
//   mine    : fp16 MFMA Gram, 64x64 tile/block, FULL K=256 staged once via
//             global_load_lds (64 KB LDS, 5-bit XOR swizzle) -> ONE vmcnt
//             barrier-drain per block (R10's 128x128/BK=64 paid 8 drains =
//             the 29 us). 4096 blocks = 16 slots/CU pipeline the drains.
//             Swapped MFMA operands: lane owns an ANCHOR; mining = in-thread
//             u64-key max + 2-step q-butterfly + LDS wc-combine.
//   finalize: u64 key max across 64 chunks (full-wave butterfly) + fp32
//             distance recompute -> loss[a]
//   reduce  : single-block tree-reduce of loss[] -> out
// Accuracy: fp16 only affects WHICH indices are mined (d2 err ~0.02 vs rival
// gaps ~13); the loss values are recomputed in fp32.

#define NN 4096
#define DD 256
#define MARGIN 0.2f
#define NCHUNK 64            // one 64-col j-tile per chunk

typedef _Float16 f16;
typedef __attribute__((ext_vector_type(8))) _Float16 f16x8;
typedef __attribute__((ext_vector_type(4))) _Float16 f16x4;
typedef __attribute__((ext_vector_type(4))) float f32x4;
typedef unsigned long long u64;
typedef unsigned int u32;

// ws byte offsets
#define OFF_SQ     64                                    // 16 KB
#define OFF_EH     (OFF_SQ + NN * 4)                     // 2 MB fp16 embeddings
#define OFF_POSB   (OFF_EH + NN * DD * 2)                // 2 MB packed positives
#define OFF_PPK    (OFF_POSB + (NN * (long)NN / 8))      // 2 MB u64 pos keys [chunk][anchor]
#define OFF_PNK    (OFF_PPK + NN * NCHUNK * 8)           // 2 MB u64 neg keys
#define OFF_LOSS   (OFF_PNK + NN * NCHUNK * 8)           // 16 KB per-anchor losses

#define CONV_BLOCKS   (NN / 4)                           // 1024
#define REPACK_BLOCKS 4096
#define PREP_BLOCKS   (CONV_BLOCKS + REPACK_BLOCKS)
#define RP_WAVES      (REPACK_BLOCKS * 4)                // 16384 repack waves

// ---------------------------------------------------------------------------
// 16-B global->LDS DMA (lane dest = lds base + lane*16, wave-uniform base).
__device__ __forceinline__ void dma16(const void* g, void* l) {
  __builtin_amdgcn_global_load_lds(
      (const __attribute__((address_space(1))) void*)g,
      (__attribute__((address_space(3))) void*)l, 16, 0, 0);
}

// ---------------------------------------------------------------------------
// prep: convert (blocks 0..CONV_BLOCKS-1) | repack+sniff (the rest).
__global__ __launch_bounds__(256)
void prep_kernel(const float* __restrict__ E, const void* __restrict__ pos_raw,
                 f16* __restrict__ Eh, float* __restrict__ sq,
                 u64* __restrict__ posb) {
  const int bid = blockIdx.x;
  const int tid = threadIdx.x;
  if (bid < CONV_BLOCKS) {
    const int row = bid * 4 + (tid >> 6);
    const int lane = tid & 63;
    const float4 v = *(const float4*)&E[(size_t)row * DD + lane * 4];
    f16x4 h;
    h[0] = (f16)v.x; h[1] = (f16)v.y; h[2] = (f16)v.z; h[3] = (f16)v.w;
    *(f16x4*)&Eh[(size_t)row * DD + lane * 4] = h;
    float s = v.x * v.x + v.y * v.y + v.z * v.z + v.w * v.w;
#pragma unroll
    for (int off = 32; off > 0; off >>= 1) s += __shfl_down(s, off);
    if (lane == 0) sq[row] = s;
    return;
  }

  // ---- repack branch ----
  __shared__ int s_ev[4];
  // format sniff: evidence bits 1=u8, 2=f32, 4=f64(odd 1.0-hi), 8=odd-dword
  int ev = 0;
#pragma unroll
  for (int k = 0; k < 16; ++k) {
    const int di = tid + (k << 8);                       // 4096 dwords = 16 KB
    const u32 v = ((const u32*)pos_raw)[di];
    if (v & 0xffffff00u) ev |= 1;
    if (v == 0x3f800000u) ev |= 2;
    if (di & 1) {
      if (v == 0x3ff00000u) ev |= 4;
      if (v) ev |= 8;
    }
  }
#pragma unroll
  for (int off = 32; off > 0; off >>= 1) ev |= __shfl_xor(ev, off);
  if ((tid & 63) == 0) s_ev[tid >> 6] = ev;
  __syncthreads();
  ev = s_ev[0] | s_ev[1] | s_ev[2] | s_ev[3];
  int f;                                                  // 0=i32 1=u8 2=f32 3=i64 4=f64
  if (ev & 2) f = 2;
  else if (ev & 4) f = 4;
  else if (ev & 1) f = 1;
  else if (ev & 8) f = 0;
  else f = 3;

  const int lane = tid & 63;
  const int wid = (bid - CONV_BLOCKS) * 4 + (tid >> 6);   // 0..RP_WAVES-1

  if (f == 0 || f == 2) {
    // 4 elems/lane (16 B), 256 elems/wave-span -> 4 output words per span.
    const int nspan = NN * NN / 256;                      // 65536
    for (int s = wid; s < nspan; s += RP_WAVES) {
      const size_t eb = (size_t)s * 256 + lane * 4;
      u32 p;
      if (f == 0) {
        const uint4 v = *(const uint4*)((const u32*)pos_raw + eb);
        p = (v.x != 0u) | ((v.y != 0u) << 1) | ((v.z != 0u) << 2) | ((v.w != 0u) << 3);
      } else {
        const float4 v = *(const float4*)((const float*)pos_raw + eb);
        p = (v.x != 0.f) | ((v.y != 0.f) << 1) | ((v.z != 0.f) << 2) | ((v.w != 0.f) << 3);
      }
      u64 val = (u64)p << (4 * (lane & 15));
#pragma unroll
      for (int off = 1; off < 16; off <<= 1) val |= __shfl_xor(val, off);
      if ((lane & 15) == 0) posb[(size_t)s * 4 + (lane >> 4)] = val;
    }
  } else if (f == 1) {
    // 16 bytes/lane, 1024 elems/wave-span -> 16 output words per span.
    const int nspan = NN * NN / 1024;                     // 16384
    for (int s = wid; s < nspan; s += RP_WAVES) {
      const size_t eb = (size_t)s * 1024 + lane * 16;
      const uint4 v = *(const uint4*)((const unsigned char*)pos_raw + eb);
      u32 bits = 0;
      const u32 d[4] = {v.x, v.y, v.z, v.w};
#pragma unroll
      for (int c = 0; c < 4; ++c)
#pragma unroll
        for (int b = 0; b < 4; ++b)
          bits |= (u32)(((d[c] >> (8 * b)) & 0xffu) != 0u) << (c * 4 + b);
      u64 val = (u64)bits << (16 * (lane & 3));
#pragma unroll
      for (int off = 1; off < 4; off <<= 1) val |= __shfl_xor(val, off);
      if ((lane & 3) == 0) posb[(size_t)s * 16 + (lane >> 2)] = val;
    }
  } else {
    // scalar ballot fallback (i64 / f64 — improbable encodings)
    const long long stride = (long long)REPACK_BLOCKS * 256;
    const long long base = (long long)(bid - CONV_BLOCKS) * 256 + tid;
#pragma unroll
    for (int it = 0; it < 16; ++it) {
      const long long idx = base + it * stride;
      bool p;
      if (f == 3) p = ((const u64*)pos_raw)[idx] != 0ull;
      else        p = ((const double*)pos_raw)[idx] != 0.0;
      const u64 w = __ballot(p);
      if ((tid & 63) == 0) posb[idx >> 6] = w;
    }
  }
}

// ---------------------------------------------------------------------------
// MFMA Gram + batch-hard mining, stage-once. 64x64 tile/block; 4 waves in a
// 2x2 grid (wr = anchor 32-half, wc = j 32-half), each wave a 2x2 grid of
// 16x16x32_f16 MFMAs over 8 K-chunks. FULL K staged once: A,B = 64 rows x
// 512 B each (64 KB LDS). Row layout: 32 granules (16 B) at slot g^(r&31) —
// both DMA writes and frag ds_read_b128 hit each 4-bank group exactly 8x
// (minimum phases, conflict-free). One vmcnt drain per block.
// Swapped MFMA operands (acc = mfma(bf, af)):
//   acc[mt][nt](q,r,lx) = S[j0 + wc*32 + nt*16 + q*4 + r][i0 + wr*32 + mt*16 + lx]
__global__ __launch_bounds__(256)
void mine_kernel(const f16* __restrict__ Eh, const float* __restrict__ sq,
                 const u64* __restrict__ posb,
                 u64* __restrict__ part_p, u64* __restrict__ part_n) {
  __shared__ union {
    struct { f16 A[64 * 256]; f16 B[64 * 256]; } t;                   // 64 KB
    struct { u64 pk[2][64]; u64 nk[2][64]; } r;                       // 2 KB
  } sm;

  const int tid = threadIdx.x;
  const int lane = tid & 63, wave = tid >> 6;
  const int lx = lane & 15, q = lane >> 4;
  const int wr = wave >> 1, wc = wave & 1;
  const int ib = blockIdx.x & 63, jb = blockIdx.x >> 6;
  const int i0 = ib * 64, j0 = jb * 64;

  // ---- stage full K: 32 A-issues + 32 B-issues (8+8 per wave) ----
  // issue i2 covers rows 2*i2, 2*i2+1 (1 KB); lane ld: row = 2*i2 + (ld>>5),
  // slot = ld&31, fetches granule g = slot ^ (r&31) -> swizzled layout.
  const int drow = lane >> 5;            // 0..1 within issue
  const int dslot = lane & 31;
#pragma unroll
  for (int t = 0; t < 8; ++t) {
    const int i2 = wave * 8 + t;         // 0..31
    const int r = i2 * 2 + drow;         // tile row 0..63
    const int g = dslot ^ (r & 31);
    dma16(Eh + (size_t)(i0 + r) * DD + g * 8, &sm.t.A[i2 * 512]);
    dma16(Eh + (size_t)(j0 + r) * DD + g * 8, &sm.t.B[i2 * 512]);
  }
  __syncthreads();                        // the ONE vmcnt drain

  f32x4 acc[2][2];
#pragma unroll
  for (int mt = 0; mt < 2; ++mt)
#pragma unroll
    for (int nt = 0; nt < 2; ++nt) acc[mt][nt] = (f32x4)0.f;

#pragma unroll
  for (int ks = 0; ks < 8; ++ks) {
    f16x8 af[2], bf[2];
#pragma unroll
    for (int mt = 0; mt < 2; ++mt) {
      const int r = wr * 32 + mt * 16 + lx;
      af[mt] = *(const f16x8*)&sm.t.A[r * 256 + (((ks * 4 + q) ^ (r & 31)) << 3)];
    }
#pragma unroll
    for (int nt = 0; nt < 2; ++nt) {
      const int r = wc * 32 + nt * 16 + lx;
      bf[nt] = *(const f16x8*)&sm.t.B[r * 256 + (((ks * 4 + q) ^ (r & 31)) << 3)];
    }
    // SWAPPED: bf first -> D rows = j, D cols = i (anchor per lane)
#pragma unroll
    for (int mt = 0; mt < 2; ++mt)
#pragma unroll
      for (int nt = 0; nt < 2; ++nt)
        acc[mt][nt] = __builtin_amdgcn_mfma_f32_16x16x32_f16(bf[nt], af[mt], acc[mt][nt], 0, 0, 0);
  }

  // ------- epilogue: per-anchor u64-key mining -------
  // anchor (per lane, per mt): gi = i0 + wr*32 + mt*16 + lx
  // j (per value):             gj = j0 + wc*32 + nt*16 + q*4 + r
  float sqi_[2];
  u64 pw_[2], nw_[2];
  const int jw = j0 >> 6;                // mask word for this block's 64 cols
#pragma unroll
  for (int mt = 0; mt < 2; ++mt) {
    const int gi = i0 + wr * 32 + mt * 16 + lx;
    sqi_[mt] = sq[gi];
    const u64 pw = posb[(size_t)gi * (NN / 64) + jw];
    const u64 eye = ((gi >> 6) == jw) ? (1ull << (gi & 63)) : 0ull;
    pw_[mt] = pw;
    nw_[mt] = ~(pw | eye);
  }
  f32x4 sqjv[2];
#pragma unroll
  for (int nt = 0; nt < 2; ++nt)
    sqjv[nt] = *(const f32x4*)&sq[j0 + wc * 32 + nt * 16 + q * 4];
  const u32 jlo_base = ~(u32)(j0 + wc * 32 + q * 4);   // lo = jlo_base - (nt*16+r) = ~gj

  u64 pk[2] = {0ull, 0ull};               // key 0 = no candidate
  u64 nk[2] = {0ull, 0ull};
#pragma unroll
  for (int mt = 0; mt < 2; ++mt) {
#pragma unroll
    for (int nt = 0; nt < 2; ++nt) {
#pragma unroll
      for (int r = 0; r < 4; ++r) {
        const int c = wc * 32 + nt * 16 + q * 4 + r;   // bit within the 64-col word
        const float d2 = fmaxf(fmaf(-2.f, acc[mt][nt][r], sqi_[mt] + sqjv[nt][r]), 0.f);
        const u32 hi = __float_as_uint(d2);            // d2>=0: bits monotone
        const u32 lo = jlo_base - (u32)(nt * 16 + r);  // ~gj: ties -> smaller index
        const u64 key = ((u64)hi << 32) | lo;
        const u64 nkey = ((u64)(~hi) << 32) | lo;
        if ((pw_[mt] >> c) & 1ull) pk[mt] = key > pk[mt] ? key : pk[mt];
        if ((nw_[mt] >> c) & 1ull) nk[mt] = nkey > nk[mt] ? nkey : nk[mt];
      }
    }
  }
  // butterfly across the 4 q-groups (lanes lx, lx+16, lx+32, lx+48)
#pragma unroll
  for (int mt = 0; mt < 2; ++mt) {
#pragma unroll
    for (int off = 16; off < 64; off <<= 1) {
      u64 o = __shfl_xor(pk[mt], off);
      if (o > pk[mt]) pk[mt] = o;
      o = __shfl_xor(nk[mt], off);
      if (o > nk[mt]) nk[mt] = o;
    }
  }

  __syncthreads();  // all frag reads done; LDS becomes the reduce buffer
  if (q == 0) {
#pragma unroll
    for (int mt = 0; mt < 2; ++mt) {
      const int lr = wr * 32 + mt * 16 + lx;           // local anchor 0..63
      sm.r.pk[wc][lr] = pk[mt];
      sm.r.nk[wc][lr] = nk[mt];
    }
  }
  __syncthreads();
  if (tid < 64) {
    const u64 p0 = sm.r.pk[0][tid], p1 = sm.r.pk[1][tid];
    const u64 n0 = sm.r.nk[0][tid], n1 = sm.r.nk[1][tid];
    part_p[(size_t)jb * NN + i0 + tid] = p0 > p1 ? p0 : p1;
    part_n[(size_t)jb * NN + i0 + tid] = n0 > n1 ? n0 : n1;
  }
}

// ---------------------------------------------------------------------------
// finalize: one wave per anchor. Each lane loads one pos + one neg chunk key
// (64 chunks = 64 lanes); full-wave u64 butterflies (keys encode value+index+
// tiebreak). Unpack indices, fp32 recompute of the three distances -> loss[a].
__global__ __launch_bounds__(256)
void finalize_kernel(const float* __restrict__ E, const float* __restrict__ sq,
                     const u64* __restrict__ part_p, const u64* __restrict__ part_n,
                     float* __restrict__ loss) {
  const int tid = threadIdx.x;
  const int a = blockIdx.x * 4 + (tid >> 6);
  const int lane = tid & 63;
  u64 pkey = part_p[(size_t)lane * NN + a];
  u64 nkey = part_n[(size_t)lane * NN + a];
#pragma unroll
  for (int off = 1; off < 64; off <<= 1) {
    const u64 po = __shfl_xor(pkey, off);
    if (po > pkey) pkey = po;
    const u64 no = __shfl_xor(nkey, off);
    if (no > nkey) nkey = no;
  }
  const bool valid = (pkey != 0ull) && (nkey != 0ull);
  const int p = (int)(~(u32)pkey);           // lo = ~gj
  const int n = (int)(~(u32)nkey);
  const int pp = valid ? p : 0, nn = valid ? n : 0;

  const float4 xa = *(const float4*)&E[(size_t)a * DD + lane * 4];
  const float4 xp = *(const float4*)&E[(size_t)pp * DD + lane * 4];
  const float4 xn = *(const float4*)&E[(size_t)nn * DD + lane * 4];
  float dap = xa.x * xp.x + xa.y * xp.y + xa.z * xp.z + xa.w * xp.w;
  float dan = xa.x * xn.x + xa.y * xn.y + xa.z * xn.z + xa.w * xn.w;
  float dpn = xp.x * xn.x + xp.y * xn.y + xp.z * xn.z + xp.w * xn.w;
#pragma unroll
  for (int off = 32; off > 0; off >>= 1) {
    dap += __shfl_down(dap, off);
    dan += __shfl_down(dan, off);
    dpn += __shfl_down(dpn, off);
  }
  if (lane == 0) {
    float l = 0.f;
    if (valid) {
      const float d2ap = fmaxf(sq[a] + sq[pp] - 2.f * dap, 0.f);
      const float d2an = fmaxf(sq[a] + sq[nn] - 2.f * dan, 0.f);
      const float d2pn = fmaxf(sq[pp] + sq[nn] - 2.f * dpn, 0.f);
      l = fmaxf(sqrtf(d2ap) - fminf(sqrtf(d2an), sqrtf(d2pn)) + MARGIN, 0.f);
    }
    loss[a] = l;
  }
}

// ---------------------------------------------------------------------------
// Single block: sum + nonzero-count over loss[NN], write the scalar output.
__global__ __launch_bounds__(1024)
void reduce_kernel(const float* __restrict__ loss, float* __restrict__ out) {
  __shared__ float s_sum[16], s_cnt[16];
  const int tid = threadIdx.x;
  const float4 v = *(const float4*)&loss[tid * 4];
  float s = v.x + v.y + v.z + v.w;
  float c = (v.x > 0.f) + (v.y > 0.f) + (v.z > 0.f) + (v.w > 0.f);
#pragma unroll
  for (int off = 32; off > 0; off >>= 1) {
    s += __shfl_down(s, off);
    c += __shfl_down(c, off);
  }
  if ((tid & 63) == 0) { s_sum[tid >> 6] = s; s_cnt[tid >> 6] = c; }
  __syncthreads();
  if (tid == 0) {
    float ts = 0.f, tc = 0.f;
#pragma unroll
    for (int w = 0; w < 16; ++w) { ts += s_sum[w]; tc += s_cnt[w]; }
    out[0] = (tc > 0.f) ? (ts / fmaxf(tc, 1.f)) : 0.f;
  }
}

// ---------------------------------------------------------------------------
extern "C" void kernel_launch(void* const* d_in, const int* in_sizes, int n_in,
                              void* d_out, int out_size, void* d_ws, size_t ws_size,
                              hipStream_t stream) {
  const float* E = (const float*)d_in[0];
  const void* posm = d_in[1];
  float* out = (float*)d_out;
  char* ws = (char*)d_ws;

  float* sq = (float*)(ws + OFF_SQ);
  f16* Eh = (f16*)(ws + OFF_EH);
  u64* posb = (u64*)(ws + OFF_POSB);
  u64* ppk = (u64*)(ws + OFF_PPK);
  u64* pnk = (u64*)(ws + OFF_PNK);
  float* loss = (float*)(ws + OFF_LOSS);

  prep_kernel<<<PREP_BLOCKS, 256, 0, stream>>>(E, posm, Eh, sq, posb);
  mine_kernel<<<64 * NCHUNK, 256, 0, stream>>>(Eh, sq, posb, ppk, pnk);
  finalize_kernel<<<NN / 4, 256, 0, stream>>>(E, sq, ppk, pnk, loss);
  reduce_kernel<<<1, 1024, 0, stream>>>(loss, out);
}

// Round 12
// 165.786 us; speedup vs baseline: 1.0968x; 1.0968x over previous
//
#include <hip/hip_runtime.h>
#include <math.h>

// BatchHardTripletMarginLoss on MI355X — round 12: R10 + double-buffered DMA.
// Pipeline (all on `stream`, graph-capture safe):
//   prep    : [blocks 0..1023] E fp32->fp16 + sq
//             [blocks 1024..5119] per-block mask-format sniff + positives_mask
//             -> packed bitmask (16-B loads + shuffle-OR; neg = ~(pos|eye))
//   mine    : fp16 MFMA Gram 128x128/block, BK=64, global_load_lds staging
//             into 2x32 KB LDS buffers: DMA(chunk c+1) issues BEFORE
//             compute(chunk c), so each barrier's vmcnt drain is overlapped
//             by a full compute phase (R10 issued-then-drained back-to-back:
//             8 unhidden drains = the 29 us). Barriers 8 -> 4.
//             Swapped MFMA operands: lane owns an ANCHOR; mining = in-thread
//             u64-key max + 2-step q-butterfly + LDS wc-combine.
//   finalize: u64 key max across 32 chunks + fp32 distance recompute -> loss[a]
//   reduce  : single-block tree-reduce of loss[] -> out
// Accuracy: fp16 only affects WHICH indices are mined (d2 err ~0.02 vs rival
// gaps ~13); the loss values are recomputed in fp32.

#define NN 4096
#define DD 256
#define MARGIN 0.2f
#define NCHUNK 32            // one 128-col j-tile per chunk
#define BK 64                // K-chunk in halves (2 MFMA substeps)

typedef _Float16 f16;
typedef __attribute__((ext_vector_type(8))) _Float16 f16x8;
typedef __attribute__((ext_vector_type(4))) _Float16 f16x4;
typedef __attribute__((ext_vector_type(4))) float f32x4;
typedef unsigned long long u64;
typedef unsigned int u32;

// ws byte offsets
#define OFF_SQ     64                                    // 16 KB
#define OFF_EH     (OFF_SQ + NN * 4)                     // 2 MB fp16 embeddings
#define OFF_POSB   (OFF_EH + NN * DD * 2)                // 2 MB packed positives
#define OFF_PPK    (OFF_POSB + (NN * (long)NN / 8))      // 1 MB u64 pos keys [chunk][anchor]
#define OFF_PNK    (OFF_PPK + NN * NCHUNK * 8)           // 1 MB u64 neg keys
#define OFF_LOSS   (OFF_PNK + NN * NCHUNK * 8)           // 16 KB per-anchor losses

#define CONV_BLOCKS   (NN / 4)                           // 1024
#define REPACK_BLOCKS 4096
#define PREP_BLOCKS   (CONV_BLOCKS + REPACK_BLOCKS)
#define RP_WAVES      (REPACK_BLOCKS * 4)                // 16384 repack waves

// ---------------------------------------------------------------------------
// XOR swizzle: row stride 64 halves (128 B = all 32 banks); 16-B granule g of
// row r stored at slot g ^ swz(r). Involution: slot s holds granule s^swz(r).
__device__ __forceinline__ int swz(int r) { return (r ^ (r >> 3)) & 7; }

// 16-B global->LDS DMA (lane dest = lds base + lane*16, wave-uniform base).
__device__ __forceinline__ void dma16(const void* g, void* l) {
  __builtin_amdgcn_global_load_lds(
      (const __attribute__((address_space(1))) void*)g,
      (__attribute__((address_space(3))) void*)l, 16, 0, 0);
}

// ---------------------------------------------------------------------------
// prep: convert (blocks 0..CONV_BLOCKS-1) | repack+sniff (the rest).
__global__ __launch_bounds__(256)
void prep_kernel(const float* __restrict__ E, const void* __restrict__ pos_raw,
                 f16* __restrict__ Eh, float* __restrict__ sq,
                 u64* __restrict__ posb) {
  const int bid = blockIdx.x;
  const int tid = threadIdx.x;
  if (bid < CONV_BLOCKS) {
    const int row = bid * 4 + (tid >> 6);
    const int lane = tid & 63;
    const float4 v = *(const float4*)&E[(size_t)row * DD + lane * 4];
    f16x4 h;
    h[0] = (f16)v.x; h[1] = (f16)v.y; h[2] = (f16)v.z; h[3] = (f16)v.w;
    *(f16x4*)&Eh[(size_t)row * DD + lane * 4] = h;
    float s = v.x * v.x + v.y * v.y + v.z * v.z + v.w * v.w;
#pragma unroll
    for (int off = 32; off > 0; off >>= 1) s += __shfl_down(s, off);
    if (lane == 0) sq[row] = s;
    return;
  }

  // ---- repack branch ----
  __shared__ int s_ev[4];
  // format sniff: evidence bits 1=u8, 2=f32, 4=f64(odd 1.0-hi), 8=odd-dword
  int ev = 0;
#pragma unroll
  for (int k = 0; k < 16; ++k) {
    const int di = tid + (k << 8);                       // 4096 dwords = 16 KB
    const u32 v = ((const u32*)pos_raw)[di];
    if (v & 0xffffff00u) ev |= 1;
    if (v == 0x3f800000u) ev |= 2;
    if (di & 1) {
      if (v == 0x3ff00000u) ev |= 4;
      if (v) ev |= 8;
    }
  }
#pragma unroll
  for (int off = 32; off > 0; off >>= 1) ev |= __shfl_xor(ev, off);
  if ((tid & 63) == 0) s_ev[tid >> 6] = ev;
  __syncthreads();
  ev = s_ev[0] | s_ev[1] | s_ev[2] | s_ev[3];
  int f;                                                  // 0=i32 1=u8 2=f32 3=i64 4=f64
  if (ev & 2) f = 2;
  else if (ev & 4) f = 4;
  else if (ev & 1) f = 1;
  else if (ev & 8) f = 0;
  else f = 3;

  const int lane = tid & 63;
  const int wid = (bid - CONV_BLOCKS) * 4 + (tid >> 6);   // 0..RP_WAVES-1

  if (f == 0 || f == 2) {
    // 4 elems/lane (16 B), 256 elems/wave-span -> 4 output words per span.
    const int nspan = NN * NN / 256;                      // 65536
    for (int s = wid; s < nspan; s += RP_WAVES) {
      const size_t eb = (size_t)s * 256 + lane * 4;
      u32 p;
      if (f == 0) {
        const uint4 v = *(const uint4*)((const u32*)pos_raw + eb);
        p = (v.x != 0u) | ((v.y != 0u) << 1) | ((v.z != 0u) << 2) | ((v.w != 0u) << 3);
      } else {
        const float4 v = *(const float4*)((const float*)pos_raw + eb);
        p = (v.x != 0.f) | ((v.y != 0.f) << 1) | ((v.z != 0.f) << 2) | ((v.w != 0.f) << 3);
      }
      u64 val = (u64)p << (4 * (lane & 15));
#pragma unroll
      for (int off = 1; off < 16; off <<= 1) val |= __shfl_xor(val, off);
      if ((lane & 15) == 0) posb[(size_t)s * 4 + (lane >> 4)] = val;
    }
  } else if (f == 1) {
    // 16 bytes/lane, 1024 elems/wave-span -> 16 output words per span.
    const int nspan = NN * NN / 1024;                     // 16384
    for (int s = wid; s < nspan; s += RP_WAVES) {
      const size_t eb = (size_t)s * 1024 + lane * 16;
      const uint4 v = *(const uint4*)((const unsigned char*)pos_raw + eb);
      u32 bits = 0;
      const u32 d[4] = {v.x, v.y, v.z, v.w};
#pragma unroll
      for (int c = 0; c < 4; ++c)
#pragma unroll
        for (int b = 0; b < 4; ++b)
          bits |= (u32)(((d[c] >> (8 * b)) & 0xffu) != 0u) << (c * 4 + b);
      u64 val = (u64)bits << (16 * (lane & 3));
#pragma unroll
      for (int off = 1; off < 4; off <<= 1) val |= __shfl_xor(val, off);
      if ((lane & 3) == 0) posb[(size_t)s * 16 + (lane >> 2)] = val;
    }
  } else {
    // scalar ballot fallback (i64 / f64 — improbable encodings)
    const long long stride = (long long)REPACK_BLOCKS * 256;
    const long long base = (long long)(bid - CONV_BLOCKS) * 256 + tid;
#pragma unroll
    for (int it = 0; it < 16; ++it) {
      const long long idx = base + it * stride;
      bool p;
      if (f == 3) p = ((const u64*)pos_raw)[idx] != 0ull;
      else        p = ((const double*)pos_raw)[idx] != 0.0;
      const u64 w = __ballot(p);
      if ((tid & 63) == 0) posb[idx >> 6] = w;
    }
  }
}

// ---------------------------------------------------------------------------
// MFMA Gram + batch-hard mining, double-buffered. 128x128 tile/block; 4 waves
// in a 2x2 grid, each wave a 4x4 grid of 16x16x32_f16 MFMAs with SWAPPED
// operands:
//   acc[mt][nt](q,r,lx) = S[j0 + wc*64 + nt*16 + q*4 + r][i0 + wr*64 + mt*16 + lx]
// K-loop: issue DMA(c+1) into the other buffer BEFORE compute(c) -> the
// barrier drain at the top of iteration c+1 is overlapped by compute(c).
// Epilogue: in-thread u64-key max + 2-step q-butterfly + LDS wc-combine.
__global__ __launch_bounds__(256)
void mine_kernel(const f16* __restrict__ Eh, const float* __restrict__ sq,
                 const u64* __restrict__ posb,
                 u64* __restrict__ part_p, u64* __restrict__ part_n) {
  __shared__ union {
    struct { f16 A[2][128 * BK]; f16 B[2][128 * BK]; } t;             // 64 KB
    struct { u64 pk[2][128]; u64 nk[2][128]; } r;                     // 4 KB
  } sm;

  const int tid = threadIdx.x;
  const int lane = tid & 63, wave = tid >> 6;
  const int lx = lane & 15, q = lane >> 4;
  const int wr = wave >> 1, wc = wave & 1;
  const int ib = blockIdx.x & 31, jb = blockIdx.x >> 5;
  const int i0 = ib * 128, j0 = jb * 128;

  f32x4 acc[4][4];
#pragma unroll
  for (int mt = 0; mt < 4; ++mt)
#pragma unroll
    for (int nt = 0; nt < 4; ++nt) acc[mt][nt] = (f32x4)0.f;

  // DMA source pattern: issue i covers rows 8i..8i+7; lane ld = row 8i+(ld>>3),
  // slot ld&7, fetches granule (ld&7)^swz(row) -> swizzled layout lands right.
  const int drow = lane >> 3;            // 0..7 within issue
  const int dslot = lane & 7;

  // prologue: chunk 0 into buffer 0
#pragma unroll
  for (int t = 0; t < 4; ++t) {
    const int i = wave * 4 + t;
    const int r = i * 8 + drow;
    const int g = dslot ^ swz(r);
    dma16(Eh + (size_t)(i0 + r) * DD + g * 8, &sm.t.A[0][i * 512]);
    dma16(Eh + (size_t)(j0 + r) * DD + g * 8, &sm.t.B[0][i * 512]);
  }

#pragma unroll
  for (int c = 0; c < 4; ++c) {
    const int b = c & 1;
    __syncthreads();                      // drains DMA(c) — overlapped by compute(c-1)
    if (c < 3) {                          // issue DMA(c+1) into the other buffer
      const int kk = (c + 1) * BK;
      const int nb = (c + 1) & 1;
#pragma unroll
      for (int t = 0; t < 4; ++t) {
        const int i = wave * 4 + t;
        const int r = i * 8 + drow;
        const int g = dslot ^ swz(r);
        dma16(Eh + (size_t)(i0 + r) * DD + kk + g * 8, &sm.t.A[nb][i * 512]);
        dma16(Eh + (size_t)(j0 + r) * DD + kk + g * 8, &sm.t.B[nb][i * 512]);
      }
    }
    // compute chunk c from buffer b (DMA(c+1) in flight the whole time)
#pragma unroll
    for (int ss = 0; ss < 2; ++ss) {
      f16x8 af[4], bf[4];
#pragma unroll
      for (int mt = 0; mt < 4; ++mt) {
        const int r = wr * 64 + mt * 16 + lx;
        af[mt] = *(const f16x8*)&sm.t.A[b][r * BK + (((ss * 4 + q) ^ swz(r)) << 3)];
      }
#pragma unroll
      for (int nt = 0; nt < 4; ++nt) {
        const int r = wc * 64 + nt * 16 + lx;
        bf[nt] = *(const f16x8*)&sm.t.B[b][r * BK + (((ss * 4 + q) ^ swz(r)) << 3)];
      }
      // SWAPPED: bf first -> D rows = j, D cols = i (anchor per lane)
#pragma unroll
      for (int mt = 0; mt < 4; ++mt)
#pragma unroll
        for (int nt = 0; nt < 4; ++nt)
          acc[mt][nt] = __builtin_amdgcn_mfma_f32_16x16x32_f16(bf[nt], af[mt], acc[mt][nt], 0, 0, 0);
    }
  }

  // ------- epilogue: per-anchor u64-key mining -------
  // anchor (per lane, per mt): gi = i0 + wr*64 + mt*16 + lx
  // j (per value):             gj = j0 + wc*64 + nt*16 + q*4 + r
  float sqi_[4];
  u64 pw_[4], nw_[4];
  const int jw = (j0 + wc * 64) >> 6;    // mask word for this wave's 64 cols
#pragma unroll
  for (int mt = 0; mt < 4; ++mt) {
    const int gi = i0 + wr * 64 + mt * 16 + lx;
    sqi_[mt] = sq[gi];
    const u64 pw = posb[(size_t)gi * (NN / 64) + jw];
    const u64 eye = ((gi >> 6) == jw) ? (1ull << (gi & 63)) : 0ull;
    pw_[mt] = pw;
    nw_[mt] = ~(pw | eye);
  }
  f32x4 sqjv[4];
#pragma unroll
  for (int nt = 0; nt < 4; ++nt)
    sqjv[nt] = *(const f32x4*)&sq[j0 + wc * 64 + nt * 16 + q * 4];
  const u32 jlo_base = ~(u32)(j0 + wc * 64 + q * 4);   // lo = jlo_base - (nt*16+r) = ~gj

  u64 pk[4] = {0ull, 0ull, 0ull, 0ull};   // key 0 = no candidate
  u64 nk[4] = {0ull, 0ull, 0ull, 0ull};
#pragma unroll
  for (int mt = 0; mt < 4; ++mt) {
#pragma unroll
    for (int nt = 0; nt < 4; ++nt) {
#pragma unroll
      for (int r = 0; r < 4; ++r) {
        const int c = nt * 16 + q * 4 + r;             // bit within the 64-col window
        const float d2 = fmaxf(fmaf(-2.f, acc[mt][nt][r], sqi_[mt] + sqjv[nt][r]), 0.f);
        const u32 hi = __float_as_uint(d2);            // d2>=0: bits monotone
        const u32 lo = jlo_base - (u32)(nt * 16 + r);  // ~gj: ties -> smaller index
        const u64 key = ((u64)hi << 32) | lo;
        const u64 nkey = ((u64)(~hi) << 32) | lo;
        if ((pw_[mt] >> c) & 1ull) pk[mt] = key > pk[mt] ? key : pk[mt];
        if ((nw_[mt] >> c) & 1ull) nk[mt] = nkey > nk[mt] ? nkey : nk[mt];
      }
    }
  }
  // butterfly across the 4 q-groups (lanes lx, lx+16, lx+32, lx+48)
#pragma unroll
  for (int mt = 0; mt < 4; ++mt) {
#pragma unroll
    for (int off = 16; off < 64; off <<= 1) {
      u64 o = __shfl_xor(pk[mt], off);
      if (o > pk[mt]) pk[mt] = o;
      o = __shfl_xor(nk[mt], off);
      if (o > nk[mt]) nk[mt] = o;
    }
  }

  __syncthreads();  // all frag reads done; LDS becomes the reduce buffer
  if (q == 0) {
#pragma unroll
    for (int mt = 0; mt < 4; ++mt) {
      const int lr = wr * 64 + mt * 16 + lx;           // local anchor 0..127
      sm.r.pk[wc][lr] = pk[mt];
      sm.r.nk[wc][lr] = nk[mt];
    }
  }
  __syncthreads();
  if (tid < 128) {
    const u64 p0 = sm.r.pk[0][tid], p1 = sm.r.pk[1][tid];
    const u64 n0 = sm.r.nk[0][tid], n1 = sm.r.nk[1][tid];
    part_p[(size_t)jb * NN + i0 + tid] = p0 > p1 ? p0 : p1;
    part_n[(size_t)jb * NN + i0 + tid] = n0 > n1 ? n0 : n1;
  }
}

// ---------------------------------------------------------------------------
// finalize: one wave per anchor. Lanes 0..31 max-reduce the 32 positive-chunk
// u64 keys, lanes 32..63 the negative ones (keys already encode value+index+
// tiebreak). Unpack indices, fp32 recompute of the three distances -> loss[a].
__global__ __launch_bounds__(256)
void finalize_kernel(const float* __restrict__ E, const float* __restrict__ sq,
                     const u64* __restrict__ part_p, const u64* __restrict__ part_n,
                     float* __restrict__ loss) {
  const int tid = threadIdx.x;
  const int a = blockIdx.x * 4 + (tid >> 6);
  const int lane = tid & 63;
  const int ch = lane & 31;
  u64 key = (lane < 32) ? part_p[(size_t)ch * NN + a] : part_n[(size_t)ch * NN + a];
#pragma unroll
  for (int off = 1; off < 32; off <<= 1) {   // stays within each 32-lane half
    const u64 o = __shfl_xor(key, off);
    if (o > key) key = o;
  }
  const u64 pkey = __shfl(key, 0);
  const u64 nkey = __shfl(key, 32);
  const bool valid = (pkey != 0ull) && (nkey != 0ull);
  const int p = (int)(~(u32)pkey);           // lo = ~gj
  const int n = (int)(~(u32)nkey);
  const int pp = valid ? p : 0, nn = valid ? n : 0;

  const float4 xa = *(const float4*)&E[(size_t)a * DD + lane * 4];
  const float4 xp = *(const float4*)&E[(size_t)pp * DD + lane * 4];
  const float4 xn = *(const float4*)&E[(size_t)nn * DD + lane * 4];
  float dap = xa.x * xp.x + xa.y * xp.y + xa.z * xp.z + xa.w * xp.w;
  float dan = xa.x * xn.x + xa.y * xn.y + xa.z * xn.z + xa.w * xn.w;
  float dpn = xp.x * xn.x + xp.y * xn.y + xp.z * xn.z + xp.w * xn.w;
#pragma unroll
  for (int off = 32; off > 0; off >>= 1) {
    dap += __shfl_down(dap, off);
    dan += __shfl_down(dan, off);
    dpn += __shfl_down(dpn, off);
  }
  if (lane == 0) {
    float l = 0.f;
    if (valid) {
      const float d2ap = fmaxf(sq[a] + sq[pp] - 2.f * dap, 0.f);
      const float d2an = fmaxf(sq[a] + sq[nn] - 2.f * dan, 0.f);
      const float d2pn = fmaxf(sq[pp] + sq[nn] - 2.f * dpn, 0.f);
      l = fmaxf(sqrtf(d2ap) - fminf(sqrtf(d2an), sqrtf(d2pn)) + MARGIN, 0.f);
    }
    loss[a] = l;
  }
}

// ---------------------------------------------------------------------------
// Single block: sum + nonzero-count over loss[NN], write the scalar output.
__global__ __launch_bounds__(1024)
void reduce_kernel(const float* __restrict__ loss, float* __restrict__ out) {
  __shared__ float s_sum[16], s_cnt[16];
  const int tid = threadIdx.x;
  const float4 v = *(const float4*)&loss[tid * 4];
  float s = v.x + v.y + v.z + v.w;
  float c = (v.x > 0.f) + (v.y > 0.f) + (v.z > 0.f) + (v.w > 0.f);
#pragma unroll
  for (int off = 32; off > 0; off >>= 1) {
    s += __shfl_down(s, off);
    c += __shfl_down(c, off);
  }
  if ((tid & 63) == 0) { s_sum[tid >> 6] = s; s_cnt[tid >> 6] = c; }
  __syncthreads();
  if (tid == 0) {
    float ts = 0.f, tc = 0.f;
#pragma unroll
    for (int w = 0; w < 16; ++w) { ts += s_sum[w]; tc += s_cnt[w]; }
    out[0] = (tc > 0.f) ? (ts / fmaxf(tc, 1.f)) : 0.f;
  }
}

// ---------------------------------------------------------------------------
extern "C" void kernel_launch(void* const* d_in, const int* in_sizes, int n_in,
                              void* d_out, int out_size, void* d_ws, size_t ws_size,
                              hipStream_t stream) {
  const float* E = (const float*)d_in[0];
  const void* posm = d_in[1];
  float* out = (float*)d_out;
  char* ws = (char*)d_ws;

  float* sq = (float*)(ws + OFF_SQ);
  f16* Eh = (f16*)(ws + OFF_EH);
  u64* posb = (u64*)(ws + OFF_POSB);
  u64* ppk = (u64*)(ws + OFF_PPK);
  u64* pnk = (u64*)(ws + OFF_PNK);
  float* loss = (float*)(ws + OFF_LOSS);

  prep_kernel<<<PREP_BLOCKS, 256, 0, stream>>>(E, posm, Eh, sq, posb);
  mine_kernel<<<32 * NCHUNK, 256, 0, stream>>>(Eh, sq, posb, ppk, pnk);
  finalize_kernel<<<NN / 4, 256, 0, stream>>>(E, sq, ppk, pnk, loss);
  reduce_kernel<<<1, 1024, 0, stream>>>(loss, out);
}